// Round 8
// baseline (644.991 us; speedup 1.0000x reference)
//
#include <hip/hip_runtime.h>
#include <hip/hip_bf16.h>

// GCN forward, CSR-gather + split-bf16 MFMA + scatter-pool:
//   dinv[v] = rsqrt(1 + indeg[v])
//   y  = dinv .* (x @ W1)        fp32; 3-term split-bf16 MFMA (k_gemm1_mfma)
//   h[v] = relu(dinv[v]*(y[v] + sum_in y[u]) + b1)    (gather phase, fp32, MLP-4)
//   z  = dinv .* (h @ W2)        fp32; split-bf16 MFMA, swizzled LDS (k_gemm2_fused_mfma)
//   pool[g] = sum_v dinv[v]*(z[v] + sum_in z[u])      via CSC-by-source scatter into
//             per-block LDS [G][64] tables (k_scatterpool) + table reduce (k_redtab)

typedef __attribute__((ext_vector_type(8))) short short8;
typedef __attribute__((ext_vector_type(4))) float f32x4;

__device__ __forceinline__ unsigned short bf_rne(float f) {
  unsigned int u = __float_as_uint(f);
  return (unsigned short)((u + 0x7fffu + ((u >> 16) & 1u)) >> 16);
}
__device__ __forceinline__ float bf2f(unsigned short h) {
  return __uint_as_float(((unsigned int)h) << 16);
}

// ---------- prep: W -> transposed split-bf16 ----------
__global__ __launch_bounds__(256) void k_prepw(const float* __restrict__ W1,
    const float* __restrict__ W2,
    unsigned short* __restrict__ W1th, unsigned short* __restrict__ W1tl,
    unsigned short* __restrict__ W2th, unsigned short* __restrict__ W2tl) {
  int i = blockIdx.x * 256 + threadIdx.x;
  if (i < 16384) {
    int c = i >> 7, k = i & 127;
    float f = W1[k * 128 + c];
    unsigned short hi = bf_rne(f);
    W1th[i] = hi;
    W1tl[i] = bf_rne(f - bf2f(hi));
  } else if (i < 16384 + 8192) {
    int j = i - 16384;
    int c = j >> 7, k = j & 127;
    float f = W2[k * 64 + c];
    unsigned short hi = bf_rne(f);
    W2th[j] = hi;
    W2tl[j] = bf_rne(f - bf2f(hi));
  }
}

// ---------- degree counting (both directions in one pass) ----------
__global__ __launch_bounds__(256) void k_count2(const int* __restrict__ rows,
    const int* __restrict__ cols, int* __restrict__ deg, int* __restrict__ odeg, int E) {
  int e = blockIdx.x * 256 + threadIdx.x;
  if (e < E) {
    atomicAdd(&deg[cols[e]], 1);
    atomicAdd(&odeg[rows[e]], 1);
  }
}

__global__ __launch_bounds__(256) void k_blocksum(const int* __restrict__ deg,
                                                  int* __restrict__ partial, int N) {
  __shared__ int sh[256];
  int t = threadIdx.x, i = blockIdx.x * 256 + t;
  sh[t] = (i < N) ? deg[i] : 0;
  __syncthreads();
  for (int o = 128; o > 0; o >>= 1) {
    if (t < o) sh[t] += sh[t + o];
    __syncthreads();
  }
  if (t == 0) partial[blockIdx.x] = sh[0];
}

__global__ __launch_bounds__(512) void k_scanpartial(int* __restrict__ partial, int nb) {
  __shared__ int sh[512];
  int t = threadIdx.x;
  int v = (t < nb) ? partial[t] : 0;
  sh[t] = v;
  __syncthreads();
  for (int o = 1; o < 512; o <<= 1) {
    int x = (t >= o) ? sh[t - o] : 0;
    __syncthreads();
    sh[t] += x;
    __syncthreads();
  }
  if (t < nb) partial[t] = sh[t] - v;   // exclusive
}

// exclusive scan; deg becomes cursor; optional dinv (in-degree pass only)
__global__ __launch_bounds__(256) void k_scanblock(int* __restrict__ deg,
    const int* __restrict__ partial, int* __restrict__ off,
    float* __restrict__ dinv, int N) {
  __shared__ int sh[256];
  int t = threadIdx.x, b = blockIdx.x, i = b * 256 + t;
  int v = (i < N) ? deg[i] : 0;
  sh[t] = v;
  __syncthreads();
  for (int o = 1; o < 256; o <<= 1) {
    int x = (t >= o) ? sh[t - o] : 0;
    __syncthreads();
    sh[t] += x;
    __syncthreads();
  }
  if (i < N) {
    int excl = partial[b] + sh[t] - v;
    off[i] = excl;
    deg[i] = excl;                       // becomes fill cursor
    if (dinv) dinv[i] = rsqrtf((float)v + 1.0f);   // +1 self-loop
    if (i == N - 1) off[N] = excl + v;
  }
}

// CSR by target: csrsrc[pos] = source
__global__ __launch_bounds__(256) void k_fillcsr(const int* __restrict__ rows,
    const int* __restrict__ cols, int* __restrict__ cursor,
    int* __restrict__ csrsrc, int E) {
  int e = blockIdx.x * 256 + threadIdx.x;
  if (e < E) {
    int pos = atomicAdd(&cursor[cols[e]], 1);
    csrsrc[pos] = rows[e];
  }
}

// CSC by source with pre-packed meta: (batch[dst]<<24) | (dinv[dst] bits >> 8)
// requires G <= 256 (batch id fits 8 bits) — holds: G = 256.
__global__ __launch_bounds__(256) void k_fillcsc(const int* __restrict__ rows,
    const int* __restrict__ cols, int* __restrict__ ocursor,
    const int* __restrict__ batch, const float* __restrict__ dinv,
    unsigned int* __restrict__ meta, int E) {
  int e = blockIdx.x * 256 + threadIdx.x;
  if (e < E) {
    int s = rows[e], d = cols[e];
    int pos = atomicAdd(&ocursor[s], 1);
    meta[pos] = ((unsigned int)batch[d] << 24) | (__float_as_uint(dinv[d]) >> 8);
  }
}

__global__ __launch_bounds__(256) void k_goff(const int* __restrict__ batch,
                                              int* __restrict__ goff, int N, int G) {
  int g = blockIdx.x * 256 + threadIdx.x;
  if (g > G) return;
  int lo = 0, hi = N;
  while (lo < hi) {
    int m = (lo + hi) >> 1;
    if (batch[m] < g) lo = m + 1; else hi = m;
  }
  goff[g] = lo;
}

// ---------- GEMM1 (split MFMA): y[v,:] = dinv[v] * (x[v,:] @ W1), fp32 out ----------
__global__ __launch_bounds__(256) void k_gemm1_mfma(
    const float* __restrict__ x,
    const unsigned short* __restrict__ W1th, const unsigned short* __restrict__ W1tl,
    const float* __restrict__ dinv, float* __restrict__ y, int N)
{
  const int tid = threadIdx.x;
  const int w = tid >> 6, l = tid & 63;
  const int v0 = blockIdx.x * 64;
  const int l15 = l & 15, lh = l >> 4;

  short8 bh[2][4], bl[2][4];
#pragma unroll
  for (int ct = 0; ct < 2; ++ct) {
    int colr = 32 * w + 16 * ct + l15;
#pragma unroll
    for (int ks = 0; ks < 4; ++ks) {
      bh[ct][ks] = *(const short8*)(W1th + colr * 128 + ks * 32 + 8 * lh);
      bl[ct][ks] = *(const short8*)(W1tl + colr * 128 + ks * 32 + 8 * lh);
    }
  }

#pragma unroll
  for (int rt = 0; rt < 4; ++rt) {
    int arow = v0 + rt * 16 + l15; if (arow >= N) arow = N - 1;
    const float* ar = x + (size_t)arow * 128 + 8 * lh;
    f32x4 acc0 = {0.f, 0.f, 0.f, 0.f}, acc1 = {0.f, 0.f, 0.f, 0.f};
#pragma unroll
    for (int ks = 0; ks < 4; ++ks) {
      float4 fa = *(const float4*)(ar + ks * 32);
      float4 fb = *(const float4*)(ar + ks * 32 + 4);
      short8 ah, al;
      float v0f;
      v0f = fa.x; ah[0] = (short)bf_rne(v0f); al[0] = (short)bf_rne(v0f - bf2f((unsigned short)ah[0]));
      v0f = fa.y; ah[1] = (short)bf_rne(v0f); al[1] = (short)bf_rne(v0f - bf2f((unsigned short)ah[1]));
      v0f = fa.z; ah[2] = (short)bf_rne(v0f); al[2] = (short)bf_rne(v0f - bf2f((unsigned short)ah[2]));
      v0f = fa.w; ah[3] = (short)bf_rne(v0f); al[3] = (short)bf_rne(v0f - bf2f((unsigned short)ah[3]));
      v0f = fb.x; ah[4] = (short)bf_rne(v0f); al[4] = (short)bf_rne(v0f - bf2f((unsigned short)ah[4]));
      v0f = fb.y; ah[5] = (short)bf_rne(v0f); al[5] = (short)bf_rne(v0f - bf2f((unsigned short)ah[5]));
      v0f = fb.z; ah[6] = (short)bf_rne(v0f); al[6] = (short)bf_rne(v0f - bf2f((unsigned short)ah[6]));
      v0f = fb.w; ah[7] = (short)bf_rne(v0f); al[7] = (short)bf_rne(v0f - bf2f((unsigned short)ah[7]));
      acc0 = __builtin_amdgcn_mfma_f32_16x16x32_bf16(ah, bh[0][ks], acc0, 0, 0, 0);
      acc0 = __builtin_amdgcn_mfma_f32_16x16x32_bf16(al, bh[0][ks], acc0, 0, 0, 0);
      acc0 = __builtin_amdgcn_mfma_f32_16x16x32_bf16(ah, bl[0][ks], acc0, 0, 0, 0);
      acc1 = __builtin_amdgcn_mfma_f32_16x16x32_bf16(ah, bh[1][ks], acc1, 0, 0, 0);
      acc1 = __builtin_amdgcn_mfma_f32_16x16x32_bf16(al, bh[1][ks], acc1, 0, 0, 0);
      acc1 = __builtin_amdgcn_mfma_f32_16x16x32_bf16(ah, bl[1][ks], acc1, 0, 0, 0);
    }

    int r4 = v0 + rt * 16 + lh * 4;
    float4 d4 = *(const float4*)(dinv + r4);   // overread guarded by store condition
    int col0 = 32 * w + l15;
#pragma unroll
    for (int reg = 0; reg < 4; ++reg) {
      int row = r4 + reg;
      if (row < N) {
        float dd = (reg == 0) ? d4.x : (reg == 1) ? d4.y : (reg == 2) ? d4.z : d4.w;
        y[(size_t)row * 128 + col0]      = acc0[reg] * dd;
        y[(size_t)row * 128 + col0 + 16] = acc1[reg] * dd;
      }
    }
  }
}

// ---------- GEMM2 fused with layer-1 aggregation (split MFMA, 32-node tiles, MLP-4) ----------
// Swizzle: store byte = (vn*256 + dim*2) ^ ((vn&7)<<4); read address fully composed
// BEFORE the XOR: (row*256 + ks*64 + lh*16) ^ ((row&7)<<4).
__global__ __launch_bounds__(256, 4) void k_gemm2_fused_mfma(
    const float* __restrict__ y, const int* __restrict__ off,
    const int* __restrict__ src,
    const unsigned short* __restrict__ W2th, const unsigned short* __restrict__ W2tl,
    const float* __restrict__ dinv, const float* __restrict__ b1,
    float* __restrict__ z, int N)
{
  __shared__ __align__(16) unsigned short hh[32 * 128];   // 8 KB
  __shared__ __align__(16) unsigned short hl[32 * 128];   // 8 KB
  const int tid = threadIdx.x;
  const int w = tid >> 6, l = tid & 63;
  const int v0 = blockIdx.x * 32;
  const int l15 = l & 15, lh = l >> 4;

  { // gather phase: 8 threads/node, 16 dims each, MLP-4
    int vn = tid >> 3;                 // 0..31
    int c0 = (tid & 7) << 4;           // 0..112
    int vv = v0 + vn;
    int vc = (vv < N) ? vv : N - 1;
    float acc[16];
    {
      const float4* yr = (const float4*)(y + (size_t)vc * 128 + c0);
#pragma unroll
      for (int q = 0; q < 4; ++q) {
        float4 t = yr[q];
        acc[4*q+0] = t.x; acc[4*q+1] = t.y; acc[4*q+2] = t.z; acc[4*q+3] = t.w;
      }
    }
    int e0 = off[vc], e1 = off[vc + 1];
    int last = e1 - 1;
    for (int i = e0; i < e1; i += 4) {
      int i1 = i + 1, i2 = i + 2, i3 = i + 3;
      int u0 = src[i];
      int u1 = src[i1 <= last ? i1 : last];
      int u2 = src[i2 <= last ? i2 : last];
      int u3 = src[i3 <= last ? i3 : last];
      float m1 = (i1 <= last) ? 1.f : 0.f;
      float m2 = (i2 <= last) ? 1.f : 0.f;
      float m3 = (i3 <= last) ? 1.f : 0.f;
      const float4* p0 = (const float4*)(y + (size_t)u0 * 128 + c0);
      const float4* p1 = (const float4*)(y + (size_t)u1 * 128 + c0);
      const float4* p2 = (const float4*)(y + (size_t)u2 * 128 + c0);
      const float4* p3 = (const float4*)(y + (size_t)u3 * 128 + c0);
      // issue all 16 loads, then accumulate (MLP)
      float4 t00 = p0[0], t01 = p0[1], t02 = p0[2], t03 = p0[3];
      float4 t10 = p1[0], t11 = p1[1], t12 = p1[2], t13 = p1[3];
      float4 t20 = p2[0], t21 = p2[1], t22 = p2[2], t23 = p2[3];
      float4 t30 = p3[0], t31 = p3[1], t32 = p3[2], t33 = p3[3];
      acc[0]  += t00.x + m1*t10.x + m2*t20.x + m3*t30.x;
      acc[1]  += t00.y + m1*t10.y + m2*t20.y + m3*t30.y;
      acc[2]  += t00.z + m1*t10.z + m2*t20.z + m3*t30.z;
      acc[3]  += t00.w + m1*t10.w + m2*t20.w + m3*t30.w;
      acc[4]  += t01.x + m1*t11.x + m2*t21.x + m3*t31.x;
      acc[5]  += t01.y + m1*t11.y + m2*t21.y + m3*t31.y;
      acc[6]  += t01.z + m1*t11.z + m2*t21.z + m3*t31.z;
      acc[7]  += t01.w + m1*t11.w + m2*t21.w + m3*t31.w;
      acc[8]  += t02.x + m1*t12.x + m2*t22.x + m3*t32.x;
      acc[9]  += t02.y + m1*t12.y + m2*t22.y + m3*t32.y;
      acc[10] += t02.z + m1*t12.z + m2*t22.z + m3*t32.z;
      acc[11] += t02.w + m1*t12.w + m2*t22.w + m3*t32.w;
      acc[12] += t03.x + m1*t13.x + m2*t23.x + m3*t33.x;
      acc[13] += t03.y + m1*t13.y + m2*t23.y + m3*t33.y;
      acc[14] += t03.z + m1*t13.z + m2*t23.z + m3*t33.z;
      acc[15] += t03.w + m1*t13.w + m2*t23.w + m3*t33.w;
    }
    float d = dinv[vc];
#pragma unroll
    for (int s = 0; s < 2; ++s) {
      short8 oh, ol;
#pragma unroll
      for (int j = 0; j < 8; ++j) {
        int dim = c0 + s * 8 + j;
        float hv = fmaxf(fmaf(d, acc[s*8+j], b1[dim]), 0.f);
        unsigned short hb = bf_rne(hv);
        oh[j] = (short)hb;
        ol[j] = (short)bf_rne(hv - bf2f(hb));
      }
      int byte = (vn * 256 + (c0 + s * 8) * 2) ^ ((vn & 7) << 4);
      *(short8*)((char*)hh + byte) = oh;
      *(short8*)((char*)hl + byte) = ol;
    }
  }

  // W2 B-frags (loaded after gather to cut peak VGPR; latency overlaps barrier)
  short8 bh[4], bl[4];
  {
    int colr = 16 * w + l15;
#pragma unroll
    for (int ks = 0; ks < 4; ++ks) {
      bh[ks] = *(const short8*)(W2th + colr * 128 + ks * 32 + 8 * lh);
      bl[ks] = *(const short8*)(W2tl + colr * 128 + ks * 32 + 8 * lh);
    }
  }
  __syncthreads();

  // MFMA phase: 2 row-tiles x 12 MFMAs
#pragma unroll
  for (int rt = 0; rt < 2; ++rt) {
    int row = rt * 16 + l15;
    const int swz = (row & 7) << 4;
    const int base = row * 256 + lh * 16;
    f32x4 acc = {0.f, 0.f, 0.f, 0.f};
#pragma unroll
    for (int ks = 0; ks < 4; ++ks) {
      int byte = (base + ks * 64) ^ swz;      // compose THEN xor
      short8 ah = *(const short8*)((char*)hh + byte);
      short8 al = *(const short8*)((char*)hl + byte);
      acc = __builtin_amdgcn_mfma_f32_16x16x32_bf16(ah, bh[ks], acc, 0, 0, 0);
      acc = __builtin_amdgcn_mfma_f32_16x16x32_bf16(al, bh[ks], acc, 0, 0, 0);
      acc = __builtin_amdgcn_mfma_f32_16x16x32_bf16(ah, bl[ks], acc, 0, 0, 0);
    }

    int r4 = v0 + rt * 16 + lh * 4;
    float4 d4 = *(const float4*)(dinv + r4);
    int col = 16 * w + l15;
#pragma unroll
    for (int reg = 0; reg < 4; ++reg) {
      int rr = r4 + reg;
      if (rr < N) {
        float dd = (reg == 0) ? d4.x : (reg == 1) ? d4.y : (reg == 2) ? d4.z : d4.w;
        z[(size_t)rr * 64 + col] = acc[reg] * dd;
      }
    }
  }
}

// ---------- layer-2 scatter-pool: per-block LDS [G][64] tables ----------
// grid = NB blocks x 1024 threads (16 waves). Wave = node; lanes = 64 dims.
// Per edge: lane-parallel meta load, 1 shfl broadcast, 1 conflict-free LDS ds_add.
#define NB_TAB 256
__global__ __launch_bounds__(1024) void k_scatterpool(
    const float* __restrict__ z, const int* __restrict__ ooff,
    const unsigned int* __restrict__ meta, const int* __restrict__ batch,
    const float* __restrict__ dinv, float* __restrict__ blocktab, int N)
{
  __shared__ float tab[256 * 64];   // 64 KB
  for (int i = threadIdx.x; i < 16384; i += 1024) tab[i] = 0.f;
  __syncthreads();

  const int wid = threadIdx.x >> 6, lane = threadIdx.x & 63;
  const int per = (N + NB_TAB - 1) / NB_TAB;
  const int n0 = blockIdx.x * per;
  const int n1 = (n0 + per < N) ? n0 + per : N;

  for (int u = n0 + wid; u < n1; u += 16) {
    float zd = z[(size_t)u * 64 + lane];
    int e0 = ooff[u], e1 = ooff[u + 1];
    for (int base = e0; base < e1; base += 64) {
      int idx = base + lane;
      unsigned int m = (idx < e1) ? meta[idx] : 0u;
      int cnt = e1 - base; if (cnt > 64) cnt = 64;
      for (int j = 0; j < cnt; ++j) {
        unsigned int mj = (unsigned int)__shfl((int)m, j);
        int gj = mj >> 24;
        float cj = __uint_as_float(mj << 8);
        atomicAdd(&tab[gj * 64 + lane], cj * zd);
      }
    }
    // self term
    atomicAdd(&tab[batch[u] * 64 + lane], dinv[u] * zd);
  }
  __syncthreads();
  float* dst = blocktab + (size_t)blockIdx.x * 16384;
  for (int i = threadIdx.x; i < 16384; i += 1024) dst[i] = tab[i];
}

// ---------- table reduce + mean + bias ----------
__global__ __launch_bounds__(256) void k_redtab(const float* __restrict__ blocktab,
    const int* __restrict__ goff, const float* __restrict__ b2,
    float* __restrict__ out) {
  int i = blockIdx.x * 256 + threadIdx.x;
  if (i >= 16384) return;
  float s0 = 0.f, s1 = 0.f, s2 = 0.f, s3 = 0.f;
  for (int b = 0; b < NB_TAB; b += 4) {
    s0 += blocktab[(size_t)(b + 0) * 16384 + i];
    s1 += blocktab[(size_t)(b + 1) * 16384 + i];
    s2 += blocktab[(size_t)(b + 2) * 16384 + i];
    s3 += blocktab[(size_t)(b + 3) * 16384 + i];
  }
  float s = (s0 + s1) + (s2 + s3);
  int g = i >> 6, d = i & 63;
  int n = goff[g + 1] - goff[g];
  out[i] = (n > 0) ? s / (float)n + b2[d] : 0.f;
}

extern "C" void kernel_launch(void* const* d_in, const int* in_sizes, int n_in,
                              void* d_out, int out_size, void* d_ws, size_t ws_size,
                              hipStream_t stream) {
  const float* x     = (const float*)d_in[0];
  const int*   eidx  = (const int*)d_in[1];
  const int*   batch = (const int*)d_in[2];
  const float* W1    = (const float*)d_in[3];
  const float* b1    = (const float*)d_in[4];
  const float* W2    = (const float*)d_in[5];
  const float* b2    = (const float*)d_in[6];
  float* out = (float*)d_out;

  const int N = in_sizes[2];          // 100000
  const int E = in_sizes[1] / 2;      // 640000
  const int G = out_size / 64;        // 256

  const int* rows = eidx;             // sources
  const int* cols = eidx + E;         // targets

  // workspace layout (4B units):
  // [y N*128][z N*64][W splits 24576][dinv N][deg N][odeg N][off N+1][ooff N+1]
  // [partial 512][goff G+1][csrsrc E][cscmeta E][blocktab NB_TAB*16384]
  float* y   = (float*)d_ws;
  float* z   = y + (size_t)N * 128;
  unsigned short* W1th = (unsigned short*)(z + (size_t)N * 64);
  unsigned short* W1tl = W1th + 16384;
  unsigned short* W2th = W1tl + 16384;
  unsigned short* W2tl = W2th + 8192;
  float* dinv    = (float*)(W2tl + 8192);
  int*   deg     = (int*)(dinv + N);
  int*   odeg    = deg + N;
  int*   off     = odeg + N;
  int*   ooff    = off + N + 1;
  int*   partial = ooff + N + 1;
  int*   goff    = partial + 512;
  int*   csrsrc  = goff + G + 1;
  unsigned int* cscmeta = (unsigned int*)(csrsrc + E);
  float* blocktab = (float*)(cscmeta + E);

  const int B = 256;
  const int nb = (N + B - 1) / B;     // 391 <= 512

  hipMemsetAsync(deg, 0, (size_t)2 * N * sizeof(int), stream);  // deg + odeg

  // weight prep
  k_prepw<<<(16384 + 8192 + B - 1) / B, B, 0, stream>>>(W1, W2, W1th, W1tl, W2th, W2tl);

  // degrees both directions
  k_count2<<<(E + B - 1) / B, B, 0, stream>>>(rows, cols, deg, odeg, E);
  // in-degree scan (+dinv), CSR by target
  k_blocksum<<<nb, B, 0, stream>>>(deg, partial, N);
  k_scanpartial<<<1, 512, 0, stream>>>(partial, nb);
  k_scanblock<<<nb, B, 0, stream>>>(deg, partial, off, dinv, N);
  k_fillcsr<<<(E + B - 1) / B, B, 0, stream>>>(rows, cols, deg, csrsrc, E);
  // out-degree scan, CSC by source with packed meta (needs dinv -> after in-scan)
  k_blocksum<<<nb, B, 0, stream>>>(odeg, partial, N);
  k_scanpartial<<<1, 512, 0, stream>>>(partial, nb);
  k_scanblock<<<nb, B, 0, stream>>>(odeg, partial, ooff, (float*)nullptr, N);
  k_fillcsc<<<(E + B - 1) / B, B, 0, stream>>>(rows, cols, odeg, batch, dinv, cscmeta, E);
  k_goff<<<(G + 1 + B - 1) / B, B, 0, stream>>>(batch, goff, N, G);

  // layer 1 transform (split MFMA)
  k_gemm1_mfma<<<(N + 63) / 64, B, 0, stream>>>(x, W1th, W1tl, dinv, y, N);
  // layer 1 aggregate + relu + layer 2 transform (split MFMA, 32-node tiles)
  k_gemm2_fused_mfma<<<(N + 31) / 32, B, 0, stream>>>(y, off, csrsrc, W2th, W2tl, dinv, b1, z, N);
  // layer 2 aggregate + pool via LDS tables
  k_scatterpool<<<NB_TAB, 1024, 0, stream>>>(z, ooff, cscmeta, batch, dinv, blocktab, N);
  k_redtab<<<(16384 + B - 1) / B, B, 0, stream>>>(blocktab, goff, b2, out);
}

// Round 9
// 293.237 us; speedup vs baseline: 2.1996x; 2.1996x over previous
//
#include <hip/hip_runtime.h>
#include <hip/hip_bf16.h>

// GCN forward, CSR-gather + split-bf16 MFMA, bf16 intermediates:
//   dinv[v] = rsqrt(1 + indeg[v])
//   yb = bf16(dinv .* (x @ W1))                     split-bf16 MFMA (k_gemm1_mfma)
//   h[v] = relu(dinv[v]*(yb[v] + sum_in yb[u]) + b1)  fp32 accum gather, MLP-4
//   zb = bf16(dinv .* (h @ W2))                     split-bf16 MFMA, swizzled LDS h
//   out[g] = mean_{v in g} dinv[v]*(zb[v] + sum_in zb[u]) + b2   (k_aggpool + k_final)

typedef __attribute__((ext_vector_type(8))) short short8;
typedef __attribute__((ext_vector_type(4))) float f32x4;

__device__ __forceinline__ void atomAddF(float* p, float v) { unsafeAtomicAdd(p, v); }

__device__ __forceinline__ unsigned short bf_rne(float f) {
  unsigned int u = __float_as_uint(f);
  return (unsigned short)((u + 0x7fffu + ((u >> 16) & 1u)) >> 16);
}
__device__ __forceinline__ float bf2f(unsigned short h) {
  return __uint_as_float(((unsigned int)h) << 16);
}
__device__ __forceinline__ float bf_lo(unsigned int u) { return __uint_as_float(u << 16); }
__device__ __forceinline__ float bf_hi(unsigned int u) { return __uint_as_float(u & 0xffff0000u); }

// ---------- prep: W -> transposed split-bf16 ----------
__global__ __launch_bounds__(256) void k_prepw(const float* __restrict__ W1,
    const float* __restrict__ W2,
    unsigned short* __restrict__ W1th, unsigned short* __restrict__ W1tl,
    unsigned short* __restrict__ W2th, unsigned short* __restrict__ W2tl) {
  int i = blockIdx.x * 256 + threadIdx.x;
  if (i < 16384) {
    int c = i >> 7, k = i & 127;
    float f = W1[k * 128 + c];
    unsigned short hi = bf_rne(f);
    W1th[i] = hi;
    W1tl[i] = bf_rne(f - bf2f(hi));
  } else if (i < 16384 + 8192) {
    int j = i - 16384;
    int c = j >> 7, k = j & 127;
    float f = W2[k * 64 + c];
    unsigned short hi = bf_rne(f);
    W2th[j] = hi;
    W2tl[j] = bf_rne(f - bf2f(hi));
  }
}

// ---------- degree / CSR build ----------
__global__ __launch_bounds__(256) void k_count(const int* __restrict__ col,
                                               int* __restrict__ deg, int E) {
  int e = blockIdx.x * 256 + threadIdx.x;
  if (e < E) atomicAdd(&deg[col[e]], 1);
}

__global__ __launch_bounds__(256) void k_blocksum(const int* __restrict__ deg,
                                                  int* __restrict__ partial, int N) {
  __shared__ int sh[256];
  int t = threadIdx.x, i = blockIdx.x * 256 + t;
  sh[t] = (i < N) ? deg[i] : 0;
  __syncthreads();
  for (int o = 128; o > 0; o >>= 1) {
    if (t < o) sh[t] += sh[t + o];
    __syncthreads();
  }
  if (t == 0) partial[blockIdx.x] = sh[0];
}

__global__ __launch_bounds__(512) void k_scanpartial(int* __restrict__ partial, int nb) {
  __shared__ int sh[512];
  int t = threadIdx.x;
  int v = (t < nb) ? partial[t] : 0;
  sh[t] = v;
  __syncthreads();
  for (int o = 1; o < 512; o <<= 1) {
    int x = (t >= o) ? sh[t - o] : 0;
    __syncthreads();
    sh[t] += x;
    __syncthreads();
  }
  if (t < nb) partial[t] = sh[t] - v;   // exclusive
}

__global__ __launch_bounds__(256) void k_scanblock(int* __restrict__ deg,
    const int* __restrict__ partial, int* __restrict__ off,
    float* __restrict__ dinv, int N) {
  __shared__ int sh[256];
  int t = threadIdx.x, b = blockIdx.x, i = b * 256 + t;
  int v = (i < N) ? deg[i] : 0;
  sh[t] = v;
  __syncthreads();
  for (int o = 1; o < 256; o <<= 1) {
    int x = (t >= o) ? sh[t - o] : 0;
    __syncthreads();
    sh[t] += x;
    __syncthreads();
  }
  if (i < N) {
    int excl = partial[b] + sh[t] - v;
    off[i] = excl;
    deg[i] = excl;                       // becomes fill cursor
    dinv[i] = rsqrtf((float)v + 1.0f);   // +1 self-loop
    if (i == N - 1) off[N] = excl + v;
  }
}

__global__ __launch_bounds__(256) void k_fillcsr(const int* __restrict__ rows,
    const int* __restrict__ cols, int* __restrict__ cursor,
    int* __restrict__ csrsrc, int E) {
  int e = blockIdx.x * 256 + threadIdx.x;
  if (e < E) {
    int pos = atomicAdd(&cursor[cols[e]], 1);
    csrsrc[pos] = rows[e];
  }
}

__global__ __launch_bounds__(256) void k_goff(const int* __restrict__ batch,
                                              int* __restrict__ goff, int N, int G) {
  int g = blockIdx.x * 256 + threadIdx.x;
  if (g > G) return;
  int lo = 0, hi = N;
  while (lo < hi) {
    int m = (lo + hi) >> 1;
    if (batch[m] < g) lo = m + 1; else hi = m;
  }
  goff[g] = lo;
}

// ---------- GEMM1 (split MFMA): yb[v,:] = bf16(dinv[v] * (x[v,:] @ W1)) ----------
__global__ __launch_bounds__(256) void k_gemm1_mfma(
    const float* __restrict__ x,
    const unsigned short* __restrict__ W1th, const unsigned short* __restrict__ W1tl,
    const float* __restrict__ dinv, unsigned short* __restrict__ yb, int N)
{
  const int tid = threadIdx.x;
  const int w = tid >> 6, l = tid & 63;
  const int v0 = blockIdx.x * 64;
  const int l15 = l & 15, lh = l >> 4;

  short8 bh[2][4], bl[2][4];
#pragma unroll
  for (int ct = 0; ct < 2; ++ct) {
    int colr = 32 * w + 16 * ct + l15;
#pragma unroll
    for (int ks = 0; ks < 4; ++ks) {
      bh[ct][ks] = *(const short8*)(W1th + colr * 128 + ks * 32 + 8 * lh);
      bl[ct][ks] = *(const short8*)(W1tl + colr * 128 + ks * 32 + 8 * lh);
    }
  }

#pragma unroll
  for (int rt = 0; rt < 4; ++rt) {
    int arow = v0 + rt * 16 + l15; if (arow >= N) arow = N - 1;
    const float* ar = x + (size_t)arow * 128 + 8 * lh;
    f32x4 acc0 = {0.f, 0.f, 0.f, 0.f}, acc1 = {0.f, 0.f, 0.f, 0.f};
#pragma unroll
    for (int ks = 0; ks < 4; ++ks) {
      float4 fa = *(const float4*)(ar + ks * 32);
      float4 fb = *(const float4*)(ar + ks * 32 + 4);
      short8 ah, al;
      float v0f;
      v0f = fa.x; ah[0] = (short)bf_rne(v0f); al[0] = (short)bf_rne(v0f - bf2f((unsigned short)ah[0]));
      v0f = fa.y; ah[1] = (short)bf_rne(v0f); al[1] = (short)bf_rne(v0f - bf2f((unsigned short)ah[1]));
      v0f = fa.z; ah[2] = (short)bf_rne(v0f); al[2] = (short)bf_rne(v0f - bf2f((unsigned short)ah[2]));
      v0f = fa.w; ah[3] = (short)bf_rne(v0f); al[3] = (short)bf_rne(v0f - bf2f((unsigned short)ah[3]));
      v0f = fb.x; ah[4] = (short)bf_rne(v0f); al[4] = (short)bf_rne(v0f - bf2f((unsigned short)ah[4]));
      v0f = fb.y; ah[5] = (short)bf_rne(v0f); al[5] = (short)bf_rne(v0f - bf2f((unsigned short)ah[5]));
      v0f = fb.z; ah[6] = (short)bf_rne(v0f); al[6] = (short)bf_rne(v0f - bf2f((unsigned short)ah[6]));
      v0f = fb.w; ah[7] = (short)bf_rne(v0f); al[7] = (short)bf_rne(v0f - bf2f((unsigned short)ah[7]));
      acc0 = __builtin_amdgcn_mfma_f32_16x16x32_bf16(ah, bh[0][ks], acc0, 0, 0, 0);
      acc0 = __builtin_amdgcn_mfma_f32_16x16x32_bf16(al, bh[0][ks], acc0, 0, 0, 0);
      acc0 = __builtin_amdgcn_mfma_f32_16x16x32_bf16(ah, bl[0][ks], acc0, 0, 0, 0);
      acc1 = __builtin_amdgcn_mfma_f32_16x16x32_bf16(ah, bh[1][ks], acc1, 0, 0, 0);
      acc1 = __builtin_amdgcn_mfma_f32_16x16x32_bf16(al, bh[1][ks], acc1, 0, 0, 0);
      acc1 = __builtin_amdgcn_mfma_f32_16x16x32_bf16(ah, bl[1][ks], acc1, 0, 0, 0);
    }

    int r4 = v0 + rt * 16 + lh * 4;
    float4 d4 = *(const float4*)(dinv + r4);   // overread guarded by store condition
    int col0 = 32 * w + l15;
#pragma unroll
    for (int reg = 0; reg < 4; ++reg) {
      int row = r4 + reg;
      if (row < N) {
        float dd = (reg == 0) ? d4.x : (reg == 1) ? d4.y : (reg == 2) ? d4.z : d4.w;
        yb[(size_t)row * 128 + col0]      = bf_rne(acc0[reg] * dd);
        yb[(size_t)row * 128 + col0 + 16] = bf_rne(acc1[reg] * dd);
      }
    }
  }
}

// ---------- GEMM2 fused with layer-1 aggregation (split MFMA, 32-node tiles, MLP-4) ----------
// Swizzle: store byte = (vn*256 + dim*2) ^ ((vn&7)<<4); read address fully composed
// BEFORE the XOR: (row*256 + ks*64 + lh*16) ^ ((row&7)<<4).
__global__ __launch_bounds__(256, 4) void k_gemm2_fused_mfma(
    const unsigned short* __restrict__ yb, const int* __restrict__ off,
    const int* __restrict__ src,
    const unsigned short* __restrict__ W2th, const unsigned short* __restrict__ W2tl,
    const float* __restrict__ dinv, const float* __restrict__ b1,
    unsigned short* __restrict__ zb, int N)
{
  __shared__ __align__(16) unsigned short hh[32 * 128];   // 8 KB
  __shared__ __align__(16) unsigned short hl[32 * 128];   // 8 KB
  const int tid = threadIdx.x;
  const int w = tid >> 6, l = tid & 63;
  const int v0 = blockIdx.x * 32;
  const int l15 = l & 15, lh = l >> 4;

  { // gather phase: 8 threads/node, 16 dims each, bf16 rows, fp32 accum, MLP-4
    int vn = tid >> 3;                 // 0..31
    int c0 = (tid & 7) << 4;           // dim offset 0..112
    int vv = v0 + vn;
    int vc = (vv < N) ? vv : N - 1;
    float acc[16];
    { // self row
      const uint4* yr = (const uint4*)(yb + (size_t)vc * 128 + c0);
      uint4 t0 = yr[0], t1 = yr[1];
      acc[0]  = bf_lo(t0.x); acc[1]  = bf_hi(t0.x);
      acc[2]  = bf_lo(t0.y); acc[3]  = bf_hi(t0.y);
      acc[4]  = bf_lo(t0.z); acc[5]  = bf_hi(t0.z);
      acc[6]  = bf_lo(t0.w); acc[7]  = bf_hi(t0.w);
      acc[8]  = bf_lo(t1.x); acc[9]  = bf_hi(t1.x);
      acc[10] = bf_lo(t1.y); acc[11] = bf_hi(t1.y);
      acc[12] = bf_lo(t1.z); acc[13] = bf_hi(t1.z);
      acc[14] = bf_lo(t1.w); acc[15] = bf_hi(t1.w);
    }
    int e0 = off[vc], e1 = off[vc + 1];
    int last = e1 - 1;
    for (int i = e0; i < e1; i += 4) {
      int i1 = i + 1, i2 = i + 2, i3 = i + 3;
      int u0 = src[i];
      int u1 = src[i1 <= last ? i1 : last];
      int u2 = src[i2 <= last ? i2 : last];
      int u3 = src[i3 <= last ? i3 : last];
      float m1 = (i1 <= last) ? 1.f : 0.f;
      float m2 = (i2 <= last) ? 1.f : 0.f;
      float m3 = (i3 <= last) ? 1.f : 0.f;
      const uint4* p0 = (const uint4*)(yb + (size_t)u0 * 128 + c0);
      const uint4* p1 = (const uint4*)(yb + (size_t)u1 * 128 + c0);
      const uint4* p2 = (const uint4*)(yb + (size_t)u2 * 128 + c0);
      const uint4* p3 = (const uint4*)(yb + (size_t)u3 * 128 + c0);
      // issue all 8 loads, then accumulate
      uint4 a0 = p0[0], b0 = p0[1];
      uint4 a1 = p1[0], b1v = p1[1];
      uint4 a2 = p2[0], b2v = p2[1];
      uint4 a3 = p3[0], b3v = p3[1];
      acc[0]  += bf_lo(a0.x) + m1*bf_lo(a1.x) + m2*bf_lo(a2.x) + m3*bf_lo(a3.x);
      acc[1]  += bf_hi(a0.x) + m1*bf_hi(a1.x) + m2*bf_hi(a2.x) + m3*bf_hi(a3.x);
      acc[2]  += bf_lo(a0.y) + m1*bf_lo(a1.y) + m2*bf_lo(a2.y) + m3*bf_lo(a3.y);
      acc[3]  += bf_hi(a0.y) + m1*bf_hi(a1.y) + m2*bf_hi(a2.y) + m3*bf_hi(a3.y);
      acc[4]  += bf_lo(a0.z) + m1*bf_lo(a1.z) + m2*bf_lo(a2.z) + m3*bf_lo(a3.z);
      acc[5]  += bf_hi(a0.z) + m1*bf_hi(a1.z) + m2*bf_hi(a2.z) + m3*bf_hi(a3.z);
      acc[6]  += bf_lo(a0.w) + m1*bf_lo(a1.w) + m2*bf_lo(a2.w) + m3*bf_lo(a3.w);
      acc[7]  += bf_hi(a0.w) + m1*bf_hi(a1.w) + m2*bf_hi(a2.w) + m3*bf_hi(a3.w);
      acc[8]  += bf_lo(b0.x) + m1*bf_lo(b1v.x) + m2*bf_lo(b2v.x) + m3*bf_lo(b3v.x);
      acc[9]  += bf_hi(b0.x) + m1*bf_hi(b1v.x) + m2*bf_hi(b2v.x) + m3*bf_hi(b3v.x);
      acc[10] += bf_lo(b0.y) + m1*bf_lo(b1v.y) + m2*bf_lo(b2v.y) + m3*bf_lo(b3v.y);
      acc[11] += bf_hi(b0.y) + m1*bf_hi(b1v.y) + m2*bf_hi(b2v.y) + m3*bf_hi(b3v.y);
      acc[12] += bf_lo(b0.z) + m1*bf_lo(b1v.z) + m2*bf_lo(b2v.z) + m3*bf_lo(b3v.z);
      acc[13] += bf_hi(b0.z) + m1*bf_hi(b1v.z) + m2*bf_hi(b2v.z) + m3*bf_hi(b3v.z);
      acc[14] += bf_lo(b0.w) + m1*bf_lo(b1v.w) + m2*bf_lo(b2v.w) + m3*bf_lo(b3v.w);
      acc[15] += bf_hi(b0.w) + m1*bf_hi(b1v.w) + m2*bf_hi(b2v.w) + m3*bf_hi(b3v.w);
    }
    float d = dinv[vc];
#pragma unroll
    for (int s = 0; s < 2; ++s) {
      short8 oh, ol;
#pragma unroll
      for (int j = 0; j < 8; ++j) {
        int dim = c0 + s * 8 + j;
        float hv = fmaxf(fmaf(d, acc[s*8+j], b1[dim]), 0.f);
        unsigned short hb = bf_rne(hv);
        oh[j] = (short)hb;
        ol[j] = (short)bf_rne(hv - bf2f(hb));
      }
      int byte = (vn * 256 + (c0 + s * 8) * 2) ^ ((vn & 7) << 4);
      *(short8*)((char*)hh + byte) = oh;
      *(short8*)((char*)hl + byte) = ol;
    }
  }

  // W2 B-frags hi/lo (after gather; latency overlaps barrier)
  short8 bh[4], bl[4];
  {
    int colr = 16 * w + l15;
#pragma unroll
    for (int ks = 0; ks < 4; ++ks) {
      bh[ks] = *(const short8*)(W2th + colr * 128 + ks * 32 + 8 * lh);
      bl[ks] = *(const short8*)(W2tl + colr * 128 + ks * 32 + 8 * lh);
    }
  }
  __syncthreads();

  // MFMA phase: 2 row-tiles x 12 MFMAs
#pragma unroll
  for (int rt = 0; rt < 2; ++rt) {
    int row = rt * 16 + l15;
    const int swz = (row & 7) << 4;
    const int base = row * 256 + lh * 16;
    f32x4 acc = {0.f, 0.f, 0.f, 0.f};
#pragma unroll
    for (int ks = 0; ks < 4; ++ks) {
      int byte = (base + ks * 64) ^ swz;      // compose THEN xor
      short8 ah = *(const short8*)((char*)hh + byte);
      short8 al = *(const short8*)((char*)hl + byte);
      acc = __builtin_amdgcn_mfma_f32_16x16x32_bf16(ah, bh[ks], acc, 0, 0, 0);
      acc = __builtin_amdgcn_mfma_f32_16x16x32_bf16(al, bh[ks], acc, 0, 0, 0);
      acc = __builtin_amdgcn_mfma_f32_16x16x32_bf16(ah, bl[ks], acc, 0, 0, 0);
    }

    int r4 = v0 + rt * 16 + lh * 4;
    float4 d4 = *(const float4*)(dinv + r4);
    int col = 16 * w + l15;
#pragma unroll
    for (int reg = 0; reg < 4; ++reg) {
      int rr = r4 + reg;
      if (rr < N) {
        float dd = (reg == 0) ? d4.x : (reg == 1) ? d4.y : (reg == 2) ? d4.z : d4.w;
        zb[(size_t)rr * 64 + col] = bf_rne(acc[reg] * dd);
      }
    }
  }
}

// ---------- layer-2 aggregation + pool (gather, bf16 z) ----------
// grid = G*8; block (g,seg) covers nodes lo+seg*4+w (stride 32). Wave-register
// accumulate, one wave-atomic per (block,lane) -> 32 atomics/address total.
__global__ __launch_bounds__(256) void k_aggpool(
    const unsigned short* __restrict__ zb, const int* __restrict__ off,
    const int* __restrict__ src, const float* __restrict__ dinv,
    const int* __restrict__ goff, float* __restrict__ out, int N)
{
  int g = blockIdx.x >> 3, seg = blockIdx.x & 7;
  int w = threadIdx.x >> 6, lane = threadIdx.x & 63;
  int lo = goff[g], hi = goff[g + 1];
  float acc = 0.f;
  for (int v = lo + seg * 4 + w; v < hi; v += 32) {
    float sv = bf2f(zb[(size_t)v * 64 + lane]);
    int e0 = off[v], e1 = off[v + 1];
    int last = e1 - 1;
    for (int i = e0; i < e1; i += 4) {
      int i1 = i + 1, i2 = i + 2, i3 = i + 3;
      int u0 = src[i];
      int u1 = src[i1 <= last ? i1 : last];
      int u2 = src[i2 <= last ? i2 : last];
      int u3 = src[i3 <= last ? i3 : last];
      float a0 = bf2f(zb[(size_t)u0 * 64 + lane]);
      float a1 = bf2f(zb[(size_t)u1 * 64 + lane]);
      float a2 = bf2f(zb[(size_t)u2 * 64 + lane]);
      float a3 = bf2f(zb[(size_t)u3 * 64 + lane]);
      sv += a0;
      sv += (i1 <= last) ? a1 : 0.f;
      sv += (i2 <= last) ? a2 : 0.f;
      sv += (i3 <= last) ? a3 : 0.f;
    }
    acc = fmaf(dinv[v], sv, acc);
  }
  atomAddF(out + (size_t)g * 64 + lane, acc);
}

__global__ __launch_bounds__(256) void k_final(float* __restrict__ out,
    const int* __restrict__ goff, const float* __restrict__ b2, int total) {
  int i = blockIdx.x * 256 + threadIdx.x;
  if (i >= total) return;
  int g = i >> 6, d = i & 63;
  int n = goff[g + 1] - goff[g];
  out[i] = (n > 0) ? out[i] / (float)n + b2[d] : 0.f;
}

extern "C" void kernel_launch(void* const* d_in, const int* in_sizes, int n_in,
                              void* d_out, int out_size, void* d_ws, size_t ws_size,
                              hipStream_t stream) {
  const float* x     = (const float*)d_in[0];
  const int*   eidx  = (const int*)d_in[1];
  const int*   batch = (const int*)d_in[2];
  const float* W1    = (const float*)d_in[3];
  const float* b1    = (const float*)d_in[4];
  const float* W2    = (const float*)d_in[5];
  const float* b2    = (const float*)d_in[6];
  float* out = (float*)d_out;

  const int N = in_sizes[2];          // 100000
  const int E = in_sizes[1] / 2;      // 640000
  const int G = out_size / 64;        // 256

  const int* rows = eidx;             // sources
  const int* cols = eidx + E;         // targets

  // workspace (elements):
  // [yb N*128 u16][zb N*64 u16][W1th 16384 u16][W1tl 16384 u16][W2th 8192 u16][W2tl 8192 u16]
  // [dinv N f][deg N i][off N+1 i][partial 512 i][goff G+1 i][csrsrc E i]
  unsigned short* yb  = (unsigned short*)d_ws;
  unsigned short* zb  = yb + (size_t)N * 128;
  unsigned short* W1th = zb + (size_t)N * 64;
  unsigned short* W1tl = W1th + 16384;
  unsigned short* W2th = W1tl + 16384;
  unsigned short* W2tl = W2th + 8192;
  float* dinv    = (float*)(W2tl + 8192);
  int*   deg     = (int*)(dinv + N);
  int*   off     = deg + N;
  int*   partial = off + N + 1;
  int*   goff    = partial + 512;
  int*   csrsrc  = goff + G + 1;

  const int B = 256;
  const int nb = (N + B - 1) / B;     // 391 <= 512

  hipMemsetAsync(deg, 0, (size_t)N * sizeof(int), stream);
  hipMemsetAsync(d_out, 0, (size_t)out_size * sizeof(float), stream);

  // weight prep (split-transposed bf16)
  k_prepw<<<(16384 + 8192 + B - 1) / B, B, 0, stream>>>(W1, W2, W1th, W1tl, W2th, W2tl);

  // CSR build + dinv + graph offsets
  k_count<<<(E + B - 1) / B, B, 0, stream>>>(cols, deg, E);
  k_blocksum<<<nb, B, 0, stream>>>(deg, partial, N);
  k_scanpartial<<<1, 512, 0, stream>>>(partial, nb);
  k_scanblock<<<nb, B, 0, stream>>>(deg, partial, off, dinv, N);
  k_fillcsr<<<(E + B - 1) / B, B, 0, stream>>>(rows, cols, deg, csrsrc, E);
  k_goff<<<(G + 1 + B - 1) / B, B, 0, stream>>>(batch, goff, N, G);

  // layer 1 transform (split MFMA, bf16 out)
  k_gemm1_mfma<<<(N + 63) / 64, B, 0, stream>>>(x, W1th, W1tl, dinv, yb, N);
  // layer 1 aggregate + relu + layer 2 transform (split MFMA, bf16 gather + bf16 out)
  k_gemm2_fused_mfma<<<(N + 31) / 32, B, 0, stream>>>(yb, off, csrsrc, W2th, W2tl, dinv, b1, zb, N);
  // layer 2 aggregate + pool + finalize
  k_aggpool<<<G * 8, B, 0, stream>>>(zb, off, csrsrc, dinv, goff, out, N);
  k_final<<<(out_size + B - 1) / B, B, 0, stream>>>(out, goff, b2, out_size);
}

// Round 10
// 290.641 us; speedup vs baseline: 2.2192x; 1.0089x over previous
//
#include <hip/hip_runtime.h>
#include <hip/hip_bf16.h>

// GCN forward, CSR-gather + split-bf16 MFMA, bf16 intermediates:
//   dinv[v] = rsqrt(1 + indeg[v])
//   xb = bf16(x)                                     (k_prepx, streaming)
//   yb = bf16(dinv .* (xb @ W1))    A single-bf16, B split (2-term MFMA)
//   h[v] = relu(dinv[v]*(yb[v] + sum_in yb[u]) + b1)  fp32 accum gather, MLP-4
//   zb = bf16(dinv .* (h @ W2))     h split in LDS, B split (3-term MFMA)
//   out[g] = mean_{v in g} dinv[v]*(zb[v] + sum_in zb[u]) + b2

typedef __attribute__((ext_vector_type(8))) short short8;
typedef __attribute__((ext_vector_type(4))) float f32x4;

__device__ __forceinline__ void atomAddF(float* p, float v) { unsafeAtomicAdd(p, v); }

__device__ __forceinline__ unsigned short bf_rne(float f) {
  unsigned int u = __float_as_uint(f);
  return (unsigned short)((u + 0x7fffu + ((u >> 16) & 1u)) >> 16);
}
__device__ __forceinline__ float bf2f(unsigned short h) {
  return __uint_as_float(((unsigned int)h) << 16);
}
__device__ __forceinline__ float bf_lo(unsigned int u) { return __uint_as_float(u << 16); }
__device__ __forceinline__ float bf_hi(unsigned int u) { return __uint_as_float(u & 0xffff0000u); }

// ---------- prep: x -> bf16 (streaming, coalesced) ----------
__global__ __launch_bounds__(256) void k_prepx(const float* __restrict__ x,
                                               unsigned short* __restrict__ xb, long total8) {
  long i = (long)blockIdx.x * 256 + threadIdx.x;
  if (i >= total8) return;
  const float4* in = (const float4*)(x + i * 8);
  float4 a = in[0], b = in[1];
  short8 o;
  o[0] = (short)bf_rne(a.x); o[1] = (short)bf_rne(a.y);
  o[2] = (short)bf_rne(a.z); o[3] = (short)bf_rne(a.w);
  o[4] = (short)bf_rne(b.x); o[5] = (short)bf_rne(b.y);
  o[6] = (short)bf_rne(b.z); o[7] = (short)bf_rne(b.w);
  *(short8*)(xb + i * 8) = o;
}

// ---------- prep: W -> transposed split-bf16 ----------
__global__ __launch_bounds__(256) void k_prepw(const float* __restrict__ W1,
    const float* __restrict__ W2,
    unsigned short* __restrict__ W1th, unsigned short* __restrict__ W1tl,
    unsigned short* __restrict__ W2th, unsigned short* __restrict__ W2tl) {
  int i = blockIdx.x * 256 + threadIdx.x;
  if (i < 16384) {
    int c = i >> 7, k = i & 127;
    float f = W1[k * 128 + c];
    unsigned short hi = bf_rne(f);
    W1th[i] = hi;
    W1tl[i] = bf_rne(f - bf2f(hi));
  } else if (i < 16384 + 8192) {
    int j = i - 16384;
    int c = j >> 7, k = j & 127;
    float f = W2[k * 64 + c];
    unsigned short hi = bf_rne(f);
    W2th[j] = hi;
    W2tl[j] = bf_rne(f - bf2f(hi));
  }
}

// ---------- degree / CSR build ----------
__global__ __launch_bounds__(256) void k_count(const int* __restrict__ col,
                                               int* __restrict__ deg, int E) {
  int e = blockIdx.x * 256 + threadIdx.x;
  if (e < E) atomicAdd(&deg[col[e]], 1);
}

__global__ __launch_bounds__(256) void k_blocksum(const int* __restrict__ deg,
                                                  int* __restrict__ partial, int N) {
  __shared__ int sh[256];
  int t = threadIdx.x, i = blockIdx.x * 256 + t;
  sh[t] = (i < N) ? deg[i] : 0;
  __syncthreads();
  for (int o = 128; o > 0; o >>= 1) {
    if (t < o) sh[t] += sh[t + o];
    __syncthreads();
  }
  if (t == 0) partial[blockIdx.x] = sh[0];
}

__global__ __launch_bounds__(512) void k_scanpartial(int* __restrict__ partial, int nb) {
  __shared__ int sh[512];
  int t = threadIdx.x;
  int v = (t < nb) ? partial[t] : 0;
  sh[t] = v;
  __syncthreads();
  for (int o = 1; o < 512; o <<= 1) {
    int x = (t >= o) ? sh[t - o] : 0;
    __syncthreads();
    sh[t] += x;
    __syncthreads();
  }
  if (t < nb) partial[t] = sh[t] - v;   // exclusive
}

__global__ __launch_bounds__(256) void k_scanblock(int* __restrict__ deg,
    const int* __restrict__ partial, int* __restrict__ off,
    float* __restrict__ dinv, int N) {
  __shared__ int sh[256];
  int t = threadIdx.x, b = blockIdx.x, i = b * 256 + t;
  int v = (i < N) ? deg[i] : 0;
  sh[t] = v;
  __syncthreads();
  for (int o = 1; o < 256; o <<= 1) {
    int x = (t >= o) ? sh[t - o] : 0;
    __syncthreads();
    sh[t] += x;
    __syncthreads();
  }
  if (i < N) {
    int excl = partial[b] + sh[t] - v;
    off[i] = excl;
    deg[i] = excl;                       // becomes fill cursor
    dinv[i] = rsqrtf((float)v + 1.0f);   // +1 self-loop
    if (i == N - 1) off[N] = excl + v;
  }
}

__global__ __launch_bounds__(256) void k_fillcsr(const int* __restrict__ rows,
    const int* __restrict__ cols, int* __restrict__ cursor,
    int* __restrict__ csrsrc, int E) {
  int e = blockIdx.x * 256 + threadIdx.x;
  if (e < E) {
    int pos = atomicAdd(&cursor[cols[e]], 1);
    csrsrc[pos] = rows[e];
  }
}

__global__ __launch_bounds__(256) void k_goff(const int* __restrict__ batch,
                                              int* __restrict__ goff, int N, int G) {
  int g = blockIdx.x * 256 + threadIdx.x;
  if (g > G) return;
  int lo = 0, hi = N;
  while (lo < hi) {
    int m = (lo + hi) >> 1;
    if (batch[m] < g) lo = m + 1; else hi = m;
  }
  goff[g] = lo;
}

// ---------- GEMM1: yb = bf16(dinv .* (xb @ W1)); A single, B split ----------
// 64 rows x 128 cols per block, 4 waves; wave w owns cols [32w, 32w+32).
// All 16 A-frag + 16 B-frag loads issued up front (latency overlap), zero
// conversion VALU, 64 MFMAs/wave.
__global__ __launch_bounds__(256) void k_gemm1_mfma(
    const unsigned short* __restrict__ xb,
    const unsigned short* __restrict__ W1th, const unsigned short* __restrict__ W1tl,
    const float* __restrict__ dinv, unsigned short* __restrict__ yb, int N)
{
  const int tid = threadIdx.x;
  const int w = tid >> 6, l = tid & 63;
  const int v0 = blockIdx.x * 64;
  const int l15 = l & 15, lh = l >> 4;

  // B-frags: 2 col-tiles x 4 k-steps, hi+lo
  short8 bh[2][4], bl[2][4];
#pragma unroll
  for (int ct = 0; ct < 2; ++ct) {
    int colr = 32 * w + 16 * ct + l15;
#pragma unroll
    for (int ks = 0; ks < 4; ++ks) {
      bh[ct][ks] = *(const short8*)(W1th + colr * 128 + ks * 32 + 8 * lh);
      bl[ct][ks] = *(const short8*)(W1tl + colr * 128 + ks * 32 + 8 * lh);
    }
  }

  // A-frags: 4 row-tiles x 4 k-steps (static-indexed -> registers)
  short8 af0_0, af0_1, af0_2, af0_3;
  short8 af1_0, af1_1, af1_2, af1_3;
  short8 af2_0, af2_1, af2_2, af2_3;
  short8 af3_0, af3_1, af3_2, af3_3;
  {
    int r0 = v0 + 0 * 16 + l15; if (r0 >= N) r0 = N - 1;
    int r1 = v0 + 1 * 16 + l15; if (r1 >= N) r1 = N - 1;
    int r2 = v0 + 2 * 16 + l15; if (r2 >= N) r2 = N - 1;
    int r3 = v0 + 3 * 16 + l15; if (r3 >= N) r3 = N - 1;
    const unsigned short* a0 = xb + (size_t)r0 * 128 + 8 * lh;
    const unsigned short* a1 = xb + (size_t)r1 * 128 + 8 * lh;
    const unsigned short* a2 = xb + (size_t)r2 * 128 + 8 * lh;
    const unsigned short* a3 = xb + (size_t)r3 * 128 + 8 * lh;
    af0_0 = *(const short8*)(a0);      af0_1 = *(const short8*)(a0 + 32);
    af0_2 = *(const short8*)(a0 + 64); af0_3 = *(const short8*)(a0 + 96);
    af1_0 = *(const short8*)(a1);      af1_1 = *(const short8*)(a1 + 32);
    af1_2 = *(const short8*)(a1 + 64); af1_3 = *(const short8*)(a1 + 96);
    af2_0 = *(const short8*)(a2);      af2_1 = *(const short8*)(a2 + 32);
    af2_2 = *(const short8*)(a2 + 64); af2_3 = *(const short8*)(a2 + 96);
    af3_0 = *(const short8*)(a3);      af3_1 = *(const short8*)(a3 + 32);
    af3_2 = *(const short8*)(a3 + 64); af3_3 = *(const short8*)(a3 + 96);
  }

#pragma unroll
  for (int rt = 0; rt < 4; ++rt) {
    short8 k0 = (rt == 0) ? af0_0 : (rt == 1) ? af1_0 : (rt == 2) ? af2_0 : af3_0;
    short8 k1 = (rt == 0) ? af0_1 : (rt == 1) ? af1_1 : (rt == 2) ? af2_1 : af3_1;
    short8 k2 = (rt == 0) ? af0_2 : (rt == 1) ? af1_2 : (rt == 2) ? af2_2 : af3_2;
    short8 k3 = (rt == 0) ? af0_3 : (rt == 1) ? af1_3 : (rt == 2) ? af2_3 : af3_3;
    f32x4 acc0 = {0.f, 0.f, 0.f, 0.f}, acc1 = {0.f, 0.f, 0.f, 0.f};
    acc0 = __builtin_amdgcn_mfma_f32_16x16x32_bf16(k0, bh[0][0], acc0, 0, 0, 0);
    acc1 = __builtin_amdgcn_mfma_f32_16x16x32_bf16(k0, bh[1][0], acc1, 0, 0, 0);
    acc0 = __builtin_amdgcn_mfma_f32_16x16x32_bf16(k0, bl[0][0], acc0, 0, 0, 0);
    acc1 = __builtin_amdgcn_mfma_f32_16x16x32_bf16(k0, bl[1][0], acc1, 0, 0, 0);
    acc0 = __builtin_amdgcn_mfma_f32_16x16x32_bf16(k1, bh[0][1], acc0, 0, 0, 0);
    acc1 = __builtin_amdgcn_mfma_f32_16x16x32_bf16(k1, bh[1][1], acc1, 0, 0, 0);
    acc0 = __builtin_amdgcn_mfma_f32_16x16x32_bf16(k1, bl[0][1], acc0, 0, 0, 0);
    acc1 = __builtin_amdgcn_mfma_f32_16x16x32_bf16(k1, bl[1][1], acc1, 0, 0, 0);
    acc0 = __builtin_amdgcn_mfma_f32_16x16x32_bf16(k2, bh[0][2], acc0, 0, 0, 0);
    acc1 = __builtin_amdgcn_mfma_f32_16x16x32_bf16(k2, bh[1][2], acc1, 0, 0, 0);
    acc0 = __builtin_amdgcn_mfma_f32_16x16x32_bf16(k2, bl[0][2], acc0, 0, 0, 0);
    acc1 = __builtin_amdgcn_mfma_f32_16x16x32_bf16(k2, bl[1][2], acc1, 0, 0, 0);
    acc0 = __builtin_amdgcn_mfma_f32_16x16x32_bf16(k3, bh[0][3], acc0, 0, 0, 0);
    acc1 = __builtin_amdgcn_mfma_f32_16x16x32_bf16(k3, bh[1][3], acc1, 0, 0, 0);
    acc0 = __builtin_amdgcn_mfma_f32_16x16x32_bf16(k3, bl[0][3], acc0, 0, 0, 0);
    acc1 = __builtin_amdgcn_mfma_f32_16x16x32_bf16(k3, bl[1][3], acc1, 0, 0, 0);

    int r4 = v0 + rt * 16 + lh * 4;
    float4 d4 = *(const float4*)(dinv + r4);   // overread guarded by store condition
    int col0 = 32 * w + l15;
#pragma unroll
    for (int reg = 0; reg < 4; ++reg) {
      int row = r4 + reg;
      if (row < N) {
        float dd = (reg == 0) ? d4.x : (reg == 1) ? d4.y : (reg == 2) ? d4.z : d4.w;
        yb[(size_t)row * 128 + col0]      = bf_rne(acc0[reg] * dd);
        yb[(size_t)row * 128 + col0 + 16] = bf_rne(acc1[reg] * dd);
      }
    }
  }
}

// ---------- GEMM2 fused with layer-1 aggregation (split MFMA, 32-node tiles, MLP-4) ----------
// Swizzle: store byte = (vn*256 + dim*2) ^ ((vn&7)<<4); read address fully composed
// BEFORE the XOR: (row*256 + ks*64 + lh*16) ^ ((row&7)<<4).
__global__ __launch_bounds__(256, 4) void k_gemm2_fused_mfma(
    const unsigned short* __restrict__ yb, const int* __restrict__ off,
    const int* __restrict__ src,
    const unsigned short* __restrict__ W2th, const unsigned short* __restrict__ W2tl,
    const float* __restrict__ dinv, const float* __restrict__ b1,
    unsigned short* __restrict__ zb, int N)
{
  __shared__ __align__(16) unsigned short hh[32 * 128];   // 8 KB
  __shared__ __align__(16) unsigned short hl[32 * 128];   // 8 KB
  const int tid = threadIdx.x;
  const int w = tid >> 6, l = tid & 63;
  const int v0 = blockIdx.x * 32;
  const int l15 = l & 15, lh = l >> 4;

  { // gather phase: 8 threads/node, 16 dims each, bf16 rows, fp32 accum, MLP-4
    int vn = tid >> 3;                 // 0..31
    int c0 = (tid & 7) << 4;           // dim offset 0..112
    int vv = v0 + vn;
    int vc = (vv < N) ? vv : N - 1;
    float acc[16];
    { // self row
      const uint4* yr = (const uint4*)(yb + (size_t)vc * 128 + c0);
      uint4 t0 = yr[0], t1 = yr[1];
      acc[0]  = bf_lo(t0.x); acc[1]  = bf_hi(t0.x);
      acc[2]  = bf_lo(t0.y); acc[3]  = bf_hi(t0.y);
      acc[4]  = bf_lo(t0.z); acc[5]  = bf_hi(t0.z);
      acc[6]  = bf_lo(t0.w); acc[7]  = bf_hi(t0.w);
      acc[8]  = bf_lo(t1.x); acc[9]  = bf_hi(t1.x);
      acc[10] = bf_lo(t1.y); acc[11] = bf_hi(t1.y);
      acc[12] = bf_lo(t1.z); acc[13] = bf_hi(t1.z);
      acc[14] = bf_lo(t1.w); acc[15] = bf_hi(t1.w);
    }
    int e0 = off[vc], e1 = off[vc + 1];
    int last = e1 - 1;
    for (int i = e0; i < e1; i += 4) {
      int i1 = i + 1, i2 = i + 2, i3 = i + 3;
      int u0 = src[i];
      int u1 = src[i1 <= last ? i1 : last];
      int u2 = src[i2 <= last ? i2 : last];
      int u3 = src[i3 <= last ? i3 : last];
      float m1 = (i1 <= last) ? 1.f : 0.f;
      float m2 = (i2 <= last) ? 1.f : 0.f;
      float m3 = (i3 <= last) ? 1.f : 0.f;
      const uint4* p0 = (const uint4*)(yb + (size_t)u0 * 128 + c0);
      const uint4* p1 = (const uint4*)(yb + (size_t)u1 * 128 + c0);
      const uint4* p2 = (const uint4*)(yb + (size_t)u2 * 128 + c0);
      const uint4* p3 = (const uint4*)(yb + (size_t)u3 * 128 + c0);
      // issue all 8 loads, then accumulate
      uint4 a0 = p0[0], b0 = p0[1];
      uint4 a1 = p1[0], b1v = p1[1];
      uint4 a2 = p2[0], b2v = p2[1];
      uint4 a3 = p3[0], b3v = p3[1];
      acc[0]  += bf_lo(a0.x) + m1*bf_lo(a1.x) + m2*bf_lo(a2.x) + m3*bf_lo(a3.x);
      acc[1]  += bf_hi(a0.x) + m1*bf_hi(a1.x) + m2*bf_hi(a2.x) + m3*bf_hi(a3.x);
      acc[2]  += bf_lo(a0.y) + m1*bf_lo(a1.y) + m2*bf_lo(a2.y) + m3*bf_lo(a3.y);
      acc[3]  += bf_hi(a0.y) + m1*bf_hi(a1.y) + m2*bf_hi(a2.y) + m3*bf_hi(a3.y);
      acc[4]  += bf_lo(a0.z) + m1*bf_lo(a1.z) + m2*bf_lo(a2.z) + m3*bf_lo(a3.z);
      acc[5]  += bf_hi(a0.z) + m1*bf_hi(a1.z) + m2*bf_hi(a2.z) + m3*bf_hi(a3.z);
      acc[6]  += bf_lo(a0.w) + m1*bf_lo(a1.w) + m2*bf_lo(a2.w) + m3*bf_lo(a3.w);
      acc[7]  += bf_hi(a0.w) + m1*bf_hi(a1.w) + m2*bf_hi(a2.w) + m3*bf_hi(a3.w);
      acc[8]  += bf_lo(b0.x) + m1*bf_lo(b1v.x) + m2*bf_lo(b2v.x) + m3*bf_lo(b3v.x);
      acc[9]  += bf_hi(b0.x) + m1*bf_hi(b1v.x) + m2*bf_hi(b2v.x) + m3*bf_hi(b3v.x);
      acc[10] += bf_lo(b0.y) + m1*bf_lo(b1v.y) + m2*bf_lo(b2v.y) + m3*bf_lo(b3v.y);
      acc[11] += bf_hi(b0.y) + m1*bf_hi(b1v.y) + m2*bf_hi(b2v.y) + m3*bf_hi(b3v.y);
      acc[12] += bf_lo(b0.z) + m1*bf_lo(b1v.z) + m2*bf_lo(b2v.z) + m3*bf_lo(b3v.z);
      acc[13] += bf_hi(b0.z) + m1*bf_hi(b1v.z) + m2*bf_hi(b2v.z) + m3*bf_hi(b3v.z);
      acc[14] += bf_lo(b0.w) + m1*bf_lo(b1v.w) + m2*bf_lo(b2v.w) + m3*bf_lo(b3v.w);
      acc[15] += bf_hi(b0.w) + m1*bf_hi(b1v.w) + m2*bf_hi(b2v.w) + m3*bf_hi(b3v.w);
    }
    float d = dinv[vc];
#pragma unroll
    for (int s = 0; s < 2; ++s) {
      short8 oh, ol;
#pragma unroll
      for (int j = 0; j < 8; ++j) {
        int dim = c0 + s * 8 + j;
        float hv = fmaxf(fmaf(d, acc[s*8+j], b1[dim]), 0.f);
        unsigned short hb = bf_rne(hv);
        oh[j] = (short)hb;
        ol[j] = (short)bf_rne(hv - bf2f(hb));
      }
      int byte = (vn * 256 + (c0 + s * 8) * 2) ^ ((vn & 7) << 4);
      *(short8*)((char*)hh + byte) = oh;
      *(short8*)((char*)hl + byte) = ol;
    }
  }

  // W2 B-frags hi/lo (after gather; latency overlaps barrier)
  short8 bh[4], bl[4];
  {
    int colr = 16 * w + l15;
#pragma unroll
    for (int ks = 0; ks < 4; ++ks) {
      bh[ks] = *(const short8*)(W2th + colr * 128 + ks * 32 + 8 * lh);
      bl[ks] = *(const short8*)(W2tl + colr * 128 + ks * 32 + 8 * lh);
    }
  }
  __syncthreads();

  // MFMA phase: 2 row-tiles x 12 MFMAs
#pragma unroll
  for (int rt = 0; rt < 2; ++rt) {
    int row = rt * 16 + l15;
    const int swz = (row & 7) << 4;
    const int base = row * 256 + lh * 16;
    f32x4 acc = {0.f, 0.f, 0.f, 0.f};
#pragma unroll
    for (int ks = 0; ks < 4; ++ks) {
      int byte = (base + ks * 64) ^ swz;      // compose THEN xor
      short8 ah = *(const short8*)((char*)hh + byte);
      short8 al = *(const short8*)((char*)hl + byte);
      acc = __builtin_amdgcn_mfma_f32_16x16x32_bf16(ah, bh[ks], acc, 0, 0, 0);
      acc = __builtin_amdgcn_mfma_f32_16x16x32_bf16(al, bh[ks], acc, 0, 0, 0);
      acc = __builtin_amdgcn_mfma_f32_16x16x32_bf16(ah, bl[ks], acc, 0, 0, 0);
    }

    int r4 = v0 + rt * 16 + lh * 4;
    float4 d4 = *(const float4*)(dinv + r4);
    int col = 16 * w + l15;
#pragma unroll
    for (int reg = 0; reg < 4; ++reg) {
      int rr = r4 + reg;
      if (rr < N) {
        float dd = (reg == 0) ? d4.x : (reg == 1) ? d4.y : (reg == 2) ? d4.z : d4.w;
        zb[(size_t)rr * 64 + col] = bf_rne(acc[reg] * dd);
      }
    }
  }
}

// ---------- layer-2 aggregation + pool (gather, bf16 z) ----------
__global__ __launch_bounds__(256) void k_aggpool(
    const unsigned short* __restrict__ zb, const int* __restrict__ off,
    const int* __restrict__ src, const float* __restrict__ dinv,
    const int* __restrict__ goff, float* __restrict__ out, int N)
{
  int g = blockIdx.x >> 3, seg = blockIdx.x & 7;
  int w = threadIdx.x >> 6, lane = threadIdx.x & 63;
  int lo = goff[g], hi = goff[g + 1];
  float acc = 0.f;
  for (int v = lo + seg * 4 + w; v < hi; v += 32) {
    float sv = bf2f(zb[(size_t)v * 64 + lane]);
    int e0 = off[v], e1 = off[v + 1];
    int last = e1 - 1;
    for (int i = e0; i < e1; i += 4) {
      int i1 = i + 1, i2 = i + 2, i3 = i + 3;
      int u0 = src[i];
      int u1 = src[i1 <= last ? i1 : last];
      int u2 = src[i2 <= last ? i2 : last];
      int u3 = src[i3 <= last ? i3 : last];
      float a0 = bf2f(zb[(size_t)u0 * 64 + lane]);
      float a1 = bf2f(zb[(size_t)u1 * 64 + lane]);
      float a2 = bf2f(zb[(size_t)u2 * 64 + lane]);
      float a3 = bf2f(zb[(size_t)u3 * 64 + lane]);
      sv += a0;
      sv += (i1 <= last) ? a1 : 0.f;
      sv += (i2 <= last) ? a2 : 0.f;
      sv += (i3 <= last) ? a3 : 0.f;
    }
    acc = fmaf(dinv[v], sv, acc);
  }
  atomAddF(out + (size_t)g * 64 + lane, acc);
}

__global__ __launch_bounds__(256) void k_final(float* __restrict__ out,
    const int* __restrict__ goff, const float* __restrict__ b2, int total) {
  int i = blockIdx.x * 256 + threadIdx.x;
  if (i >= total) return;
  int g = i >> 6, d = i & 63;
  int n = goff[g + 1] - goff[g];
  out[i] = (n > 0) ? out[i] / (float)n + b2[d] : 0.f;
}

extern "C" void kernel_launch(void* const* d_in, const int* in_sizes, int n_in,
                              void* d_out, int out_size, void* d_ws, size_t ws_size,
                              hipStream_t stream) {
  const float* x     = (const float*)d_in[0];
  const int*   eidx  = (const int*)d_in[1];
  const int*   batch = (const int*)d_in[2];
  const float* W1    = (const float*)d_in[3];
  const float* b1    = (const float*)d_in[4];
  const float* W2    = (const float*)d_in[5];
  const float* b2    = (const float*)d_in[6];
  float* out = (float*)d_out;

  const int N = in_sizes[2];          // 100000
  const int E = in_sizes[1] / 2;      // 640000
  const int G = out_size / 64;        // 256

  const int* rows = eidx;             // sources
  const int* cols = eidx + E;         // targets

  // workspace (elements):
  // [xb N*128 u16][yb N*128 u16][zb N*64 u16][W1th 16384][W1tl 16384][W2th 8192][W2tl 8192]
  // [dinv N f][deg N i][off N+1 i][partial 512 i][goff G+1 i][csrsrc E i]
  unsigned short* xb  = (unsigned short*)d_ws;
  unsigned short* yb  = xb + (size_t)N * 128;
  unsigned short* zb  = yb + (size_t)N * 128;
  unsigned short* W1th = zb + (size_t)N * 64;
  unsigned short* W1tl = W1th + 16384;
  unsigned short* W2th = W1tl + 16384;
  unsigned short* W2tl = W2th + 8192;
  float* dinv    = (float*)(W2tl + 8192);
  int*   deg     = (int*)(dinv + N);
  int*   off     = deg + N;
  int*   partial = off + N + 1;
  int*   goff    = partial + 512;
  int*   csrsrc  = goff + G + 1;

  const int B = 256;
  const int nb = (N + B - 1) / B;     // 391 <= 512

  hipMemsetAsync(deg, 0, (size_t)N * sizeof(int), stream);
  hipMemsetAsync(d_out, 0, (size_t)out_size * sizeof(float), stream);

  // prep: x -> bf16, W -> split-transposed bf16
  long total8 = (long)N * 16;
  k_prepx<<<(int)((total8 + B - 1) / B), B, 0, stream>>>(x, xb, total8);
  k_prepw<<<(16384 + 8192 + B - 1) / B, B, 0, stream>>>(W1, W2, W1th, W1tl, W2th, W2tl);

  // CSR build + dinv + graph offsets
  k_count<<<(E + B - 1) / B, B, 0, stream>>>(cols, deg, E);
  k_blocksum<<<nb, B, 0, stream>>>(deg, partial, N);
  k_scanpartial<<<1, 512, 0, stream>>>(partial, nb);
  k_scanblock<<<nb, B, 0, stream>>>(deg, partial, off, dinv, N);
  k_fillcsr<<<(E + B - 1) / B, B, 0, stream>>>(rows, cols, deg, csrsrc, E);
  k_goff<<<(G + 1 + B - 1) / B, B, 0, stream>>>(batch, goff, N, G);

  // layer 1 transform (A single-bf16, B split)
  k_gemm1_mfma<<<(N + 63) / 64, B, 0, stream>>>(xb, W1th, W1tl, dinv, yb, N);
  // layer 1 aggregate + relu + layer 2 transform (split MFMA)
  k_gemm2_fused_mfma<<<(N + 31) / 32, B, 0, stream>>>(yb, off, csrsrc, W2th, W2tl, dinv, b1, zb, N);
  // layer 2 aggregate + pool + finalize
  k_aggpool<<<G * 8, B, 0, stream>>>(zb, off, csrsrc, dinv, goff, out, N);
  k_final<<<(out_size + B - 1) / B, B, 0, stream>>>(out, goff, b2, out_size);
}